// Round 1
// baseline (3235.897 us; speedup 1.0000x reference)
//
#include <hip/hip_runtime.h>

#define D 128
#define N_CLS 40

// ---------------------------------------------------------------------------
// Scatter-add: agg[dst[e]] += h[src[e]]   (32 threads per edge, float4 lanes)
// ---------------------------------------------------------------------------
__global__ __launch_bounds__(256) void scatter_kernel(
    const float* __restrict__ h, const int* __restrict__ src,
    const int* __restrict__ dst, float* __restrict__ agg, int n_edges) {
  int t = blockIdx.x * 256 + threadIdx.x;
  int e = t >> 5;
  if (e >= n_edges) return;
  int c = (t & 31) << 2;
  int s = src[e], d = dst[e];
  const float4 v = *reinterpret_cast<const float4*>(h + (size_t)s * D + c);
  float* p = agg + (size_t)d * D + c;
  atomicAdd(p + 0, v.x);
  atomicAdd(p + 1, v.y);
  atomicAdd(p + 2, v.z);
  atomicAdd(p + 3, v.w);
}

// ---------------------------------------------------------------------------
// out[M,128] = relu?((H+AGG)[M,128] @ W[128,128]^T + b)
// BM=64 rows/block, BK=32, 256 threads, each thread 8 rows x 4 cols (stride-32)
// ---------------------------------------------------------------------------
template <bool RELU>
__global__ __launch_bounds__(256) void gemm128_kernel(
    const float* __restrict__ H, const float* __restrict__ AGG,
    const float* __restrict__ W, const float* __restrict__ bias,
    float* __restrict__ out, int M) {
  __shared__ float Ht[64][33];
  __shared__ float Wt[128][33];
  const int tid = threadIdx.x;
  const int row0 = blockIdx.x * 64;
  const int tr = tid >> 5;   // 0..7 row group (wave-uniform per half-wave)
  const int tc = tid & 31;   // col base; cols tc + 32*ci  -> conflict-free LDS

  float acc[8][4] = {};

  for (int k0 = 0; k0 < D; k0 += 32) {
    // stage Ht = H + AGG  (64 x 32 floats = 512 float4 slots)
#pragma unroll
    for (int i = 0; i < 2; ++i) {
      int idx = tid + i * 256;
      int r = idx >> 3;
      int kk = (idx & 7) << 2;
      int gr = row0 + r;
      float4 hv = make_float4(0.f, 0.f, 0.f, 0.f);
      if (gr < M) {
        const float4 a = *reinterpret_cast<const float4*>(H + (size_t)gr * D + k0 + kk);
        const float4 g = *reinterpret_cast<const float4*>(AGG + (size_t)gr * D + k0 + kk);
        hv.x = a.x + g.x; hv.y = a.y + g.y; hv.z = a.z + g.z; hv.w = a.w + g.w;
      }
      Ht[r][kk + 0] = hv.x; Ht[r][kk + 1] = hv.y;
      Ht[r][kk + 2] = hv.z; Ht[r][kk + 3] = hv.w;
    }
    // stage Wt  (128 x 32 floats = 1024 float4 slots)
#pragma unroll
    for (int i = 0; i < 4; ++i) {
      int idx = tid + i * 256;
      int c = idx >> 3;
      int kk = (idx & 7) << 2;
      const float4 wv = *reinterpret_cast<const float4*>(W + (size_t)c * D + k0 + kk);
      Wt[c][kk + 0] = wv.x; Wt[c][kk + 1] = wv.y;
      Wt[c][kk + 2] = wv.z; Wt[c][kk + 3] = wv.w;
    }
    __syncthreads();

#pragma unroll
    for (int kk = 0; kk < 32; ++kk) {
      float hv[8];
#pragma unroll
      for (int ri = 0; ri < 8; ++ri) hv[ri] = Ht[tr * 8 + ri][kk];  // broadcast
      float wv[4];
#pragma unroll
      for (int ci = 0; ci < 4; ++ci) wv[ci] = Wt[tc + 32 * ci][kk]; // bank tc+kk
#pragma unroll
      for (int ri = 0; ri < 8; ++ri)
#pragma unroll
        for (int ci = 0; ci < 4; ++ci)
          acc[ri][ci] = fmaf(hv[ri], wv[ci], acc[ri][ci]);
    }
    __syncthreads();
  }

#pragma unroll
  for (int ri = 0; ri < 8; ++ri) {
    int gr = row0 + tr * 8 + ri;
    if (gr >= M) continue;
#pragma unroll
    for (int ci = 0; ci < 4; ++ci) {
      int c = tc + 32 * ci;
      float v = acc[ri][ci] + bias[c];
      if (RELU) v = fmaxf(v, 0.f);
      out[(size_t)gr * D + c] = v;
    }
  }
}

// ---------------------------------------------------------------------------
// out[M,40] = (H+AGG)[M,128] @ W[40,128]^T + b   (final projection, no relu)
// BM=64 rows/block, 256 threads: 4 threads/row, 10 cols each
// ---------------------------------------------------------------------------
__global__ __launch_bounds__(256) void gemm40_kernel(
    const float* __restrict__ H, const float* __restrict__ AGG,
    const float* __restrict__ W, const float* __restrict__ bias,
    float* __restrict__ out, int M) {
  __shared__ float Ht[64][33];
  __shared__ float Wt[40][33];
  const int tid = threadIdx.x;
  const int row0 = blockIdx.x * 64;
  const int r = tid >> 2;          // 0..63
  const int cg = (tid & 3) * 10;   // col group base

  float acc[10] = {};

  for (int k0 = 0; k0 < D; k0 += 32) {
#pragma unroll
    for (int i = 0; i < 2; ++i) {
      int idx = tid + i * 256;
      int rr = idx >> 3;
      int kk = (idx & 7) << 2;
      int gr = row0 + rr;
      float4 hv = make_float4(0.f, 0.f, 0.f, 0.f);
      if (gr < M) {
        const float4 a = *reinterpret_cast<const float4*>(H + (size_t)gr * D + k0 + kk);
        const float4 g = *reinterpret_cast<const float4*>(AGG + (size_t)gr * D + k0 + kk);
        hv.x = a.x + g.x; hv.y = a.y + g.y; hv.z = a.z + g.z; hv.w = a.w + g.w;
      }
      Ht[rr][kk + 0] = hv.x; Ht[rr][kk + 1] = hv.y;
      Ht[rr][kk + 2] = hv.z; Ht[rr][kk + 3] = hv.w;
    }
    // Wt: 40 x 32 floats = 320 float4 slots
#pragma unroll
    for (int i = 0; i < 2; ++i) {
      int idx = tid + i * 256;
      if (idx < 320) {
        int c = idx >> 3;
        int kk = (idx & 7) << 2;
        const float4 wv = *reinterpret_cast<const float4*>(W + (size_t)c * D + k0 + kk);
        Wt[c][kk + 0] = wv.x; Wt[c][kk + 1] = wv.y;
        Wt[c][kk + 2] = wv.z; Wt[c][kk + 3] = wv.w;
      }
    }
    __syncthreads();

#pragma unroll
    for (int kk = 0; kk < 32; ++kk) {
      float hv = Ht[r][kk];
#pragma unroll
      for (int ci = 0; ci < 10; ++ci)
        acc[ci] = fmaf(hv, Wt[cg + ci][kk], acc[ci]);
    }
    __syncthreads();
  }

  int gr = row0 + r;
  if (gr < M) {
#pragma unroll
    for (int ci = 0; ci < 10; ++ci)
      out[(size_t)gr * N_CLS + cg + ci] = acc[ci] + bias[cg + ci];
  }
}

// ---------------------------------------------------------------------------
extern "C" void kernel_launch(void* const* d_in, const int* in_sizes, int n_in,
                              void* d_out, int out_size, void* d_ws, size_t ws_size,
                              hipStream_t stream) {
  const float* x  = (const float*)d_in[0];
  const int*   src = (const int*)d_in[1];
  const int*   dst = (const int*)d_in[2];
  const float* W0 = (const float*)d_in[3];
  const float* b0 = (const float*)d_in[4];
  const float* W1 = (const float*)d_in[5];
  const float* b1 = (const float*)d_in[6];
  const float* W2 = (const float*)d_in[7];
  const float* b2 = (const float*)d_in[8];
  float* out = (float*)d_out;

  const int M = in_sizes[0] / D;   // 50000
  const int E = in_sizes[1];       // 600000

  float* agg = (float*)d_ws;
  float* h1  = agg + (size_t)M * D;
  float* h2  = h1 + (size_t)M * D;
  const size_t aggBytes = (size_t)M * D * sizeof(float);

  const int scatterBlocks = (E * 32 + 255) / 256;
  const int gemmBlocks = (M + 63) / 64;

  // Layer 0: agg = segsum(x[src], dst); h1 = relu((x+agg)@W0^T + b0)
  hipMemsetAsync(agg, 0, aggBytes, stream);
  scatter_kernel<<<scatterBlocks, 256, 0, stream>>>(x, src, dst, agg, E);
  gemm128_kernel<true><<<gemmBlocks, 256, 0, stream>>>(x, agg, W0, b0, h1, M);

  // Layer 1
  hipMemsetAsync(agg, 0, aggBytes, stream);
  scatter_kernel<<<scatterBlocks, 256, 0, stream>>>(h1, src, dst, agg, E);
  gemm128_kernel<true><<<gemmBlocks, 256, 0, stream>>>(h1, agg, W1, b1, h2, M);

  // Layer 2 (output projection, no relu)
  hipMemsetAsync(agg, 0, aggBytes, stream);
  scatter_kernel<<<scatterBlocks, 256, 0, stream>>>(h2, src, dst, agg, E);
  gemm40_kernel<<<gemmBlocks, 256, 0, stream>>>(h2, agg, W2, b2, out, M);
}

// Round 2
// 530.718 us; speedup vs baseline: 6.0972x; 6.0972x over previous
//
#include <hip/hip_runtime.h>

#define D 128
#define N_CLS 40

// ---------------------------------------------------------------------------
// CSR build step 1: counts[dst[e]]++
// ---------------------------------------------------------------------------
__global__ __launch_bounds__(256) void count_kernel(
    const int* __restrict__ dst, int* __restrict__ counts, int n_edges) {
  int e = blockIdx.x * 256 + threadIdx.x;
  if (e < n_edges) atomicAdd(&counts[dst[e]], 1);
}

// ---------------------------------------------------------------------------
// CSR build step 2: exclusive prefix sum (single block, 1024 threads).
// Writes row_start[i]; re-writes counts[i] = exclusive offset (cursor init).
// ---------------------------------------------------------------------------
__global__ __launch_bounds__(1024) void scan_kernel(
    int* __restrict__ counts, int* __restrict__ row_start, int n, int n_edges) {
  __shared__ int part[1024];
  const int t = threadIdx.x;
  const int chunk = (n + 1023) >> 10;
  const int lo = t * chunk;
  const int hi = min(lo + chunk, n);
  int sum = 0;
  for (int i = lo; i < hi; ++i) sum += counts[i];
  part[t] = sum;
  __syncthreads();
  for (int off = 1; off < 1024; off <<= 1) {
    int other = (t >= off) ? part[t - off] : 0;
    __syncthreads();
    part[t] += other;
    __syncthreads();
  }
  int excl = part[t] - sum;
  int o = excl;
  for (int i = lo; i < hi; ++i) {
    int c = counts[i];
    row_start[i] = o;
    counts[i] = o;  // cursor for fill_kernel
    o += c;
  }
  if (t == 0) row_start[n] = n_edges;
}

// ---------------------------------------------------------------------------
// CSR build step 3: col_idx[cursor[dst[e]]++] = src[e]
// ---------------------------------------------------------------------------
__global__ __launch_bounds__(256) void fill_kernel(
    const int* __restrict__ src, const int* __restrict__ dst,
    int* __restrict__ cursor, int* __restrict__ col_idx, int n_edges) {
  int e = blockIdx.x * 256 + threadIdx.x;
  if (e < n_edges) {
    int p = atomicAdd(&cursor[dst[e]], 1);
    col_idx[p] = src[e];
  }
}

// ---------------------------------------------------------------------------
// Gather-aggregate: out[n] = h[n] + sum_{j in row n} h[col_idx[j]]
// One wave (64 lanes) per node; float2 per lane covers D=128.
// ---------------------------------------------------------------------------
__global__ __launch_bounds__(256) void gather_kernel(
    const float* __restrict__ h, const int* __restrict__ row_start,
    const int* __restrict__ col_idx, float* __restrict__ out, int n_nodes) {
  int wave = (blockIdx.x * 256 + threadIdx.x) >> 6;
  int lane = threadIdx.x & 63;
  if (wave >= n_nodes) return;
  const float2* hp = reinterpret_cast<const float2*>(h);
  int s = row_start[wave];
  int e = row_start[wave + 1];
  float2 acc = hp[(size_t)wave * 64 + lane];  // self term
  // unroll-by-2 with independent partials for ILP
  float2 acc2 = make_float2(0.f, 0.f);
  int j = s;
  for (; j + 1 < e; j += 2) {
    int u0 = col_idx[j];
    int u1 = col_idx[j + 1];
    float2 v0 = hp[(size_t)u0 * 64 + lane];
    float2 v1 = hp[(size_t)u1 * 64 + lane];
    acc.x += v0.x; acc.y += v0.y;
    acc2.x += v1.x; acc2.y += v1.y;
  }
  if (j < e) {
    int u = col_idx[j];
    float2 v = hp[(size_t)u * 64 + lane];
    acc.x += v.x; acc.y += v.y;
  }
  acc.x += acc2.x; acc.y += acc2.y;
  reinterpret_cast<float2*>(out)[(size_t)wave * 64 + lane] = acc;
}

// ---------------------------------------------------------------------------
// out[M,128] = relu?(HS[M,128] @ W[128,128]^T + b)
// BM=64 rows/block, BK=32, 256 threads, each thread 8 rows x 4 cols
// ---------------------------------------------------------------------------
template <bool RELU>
__global__ __launch_bounds__(256) void gemm128_kernel(
    const float* __restrict__ HS, const float* __restrict__ W,
    const float* __restrict__ bias, float* __restrict__ out, int M) {
  __shared__ float Ht[64][33];
  __shared__ float Wt[128][33];
  const int tid = threadIdx.x;
  const int row0 = blockIdx.x * 64;
  const int tr = tid >> 5;
  const int tc = tid & 31;

  float acc[8][4] = {};

  for (int k0 = 0; k0 < D; k0 += 32) {
#pragma unroll
    for (int i = 0; i < 2; ++i) {
      int idx = tid + i * 256;
      int r = idx >> 3;
      int kk = (idx & 7) << 2;
      int gr = row0 + r;
      float4 hv = make_float4(0.f, 0.f, 0.f, 0.f);
      if (gr < M)
        hv = *reinterpret_cast<const float4*>(HS + (size_t)gr * D + k0 + kk);
      Ht[r][kk + 0] = hv.x; Ht[r][kk + 1] = hv.y;
      Ht[r][kk + 2] = hv.z; Ht[r][kk + 3] = hv.w;
    }
#pragma unroll
    for (int i = 0; i < 4; ++i) {
      int idx = tid + i * 256;
      int c = idx >> 3;
      int kk = (idx & 7) << 2;
      const float4 wv = *reinterpret_cast<const float4*>(W + (size_t)c * D + k0 + kk);
      Wt[c][kk + 0] = wv.x; Wt[c][kk + 1] = wv.y;
      Wt[c][kk + 2] = wv.z; Wt[c][kk + 3] = wv.w;
    }
    __syncthreads();

#pragma unroll
    for (int kk = 0; kk < 32; ++kk) {
      float hv[8];
#pragma unroll
      for (int ri = 0; ri < 8; ++ri) hv[ri] = Ht[tr * 8 + ri][kk];
      float wv[4];
#pragma unroll
      for (int ci = 0; ci < 4; ++ci) wv[ci] = Wt[tc + 32 * ci][kk];
#pragma unroll
      for (int ri = 0; ri < 8; ++ri)
#pragma unroll
        for (int ci = 0; ci < 4; ++ci)
          acc[ri][ci] = fmaf(hv[ri], wv[ci], acc[ri][ci]);
    }
    __syncthreads();
  }

#pragma unroll
  for (int ri = 0; ri < 8; ++ri) {
    int gr = row0 + tr * 8 + ri;
    if (gr >= M) continue;
#pragma unroll
    for (int ci = 0; ci < 4; ++ci) {
      int c = tc + 32 * ci;
      float v = acc[ri][ci] + bias[c];
      if (RELU) v = fmaxf(v, 0.f);
      out[(size_t)gr * D + c] = v;
    }
  }
}

// ---------------------------------------------------------------------------
// out[M,40] = HS[M,128] @ W[40,128]^T + b   (final projection, no relu)
// ---------------------------------------------------------------------------
__global__ __launch_bounds__(256) void gemm40_kernel(
    const float* __restrict__ HS, const float* __restrict__ W,
    const float* __restrict__ bias, float* __restrict__ out, int M) {
  __shared__ float Ht[64][33];
  __shared__ float Wt[40][33];
  const int tid = threadIdx.x;
  const int row0 = blockIdx.x * 64;
  const int r = tid >> 2;
  const int cg = (tid & 3) * 10;

  float acc[10] = {};

  for (int k0 = 0; k0 < D; k0 += 32) {
#pragma unroll
    for (int i = 0; i < 2; ++i) {
      int idx = tid + i * 256;
      int rr = idx >> 3;
      int kk = (idx & 7) << 2;
      int gr = row0 + rr;
      float4 hv = make_float4(0.f, 0.f, 0.f, 0.f);
      if (gr < M)
        hv = *reinterpret_cast<const float4*>(HS + (size_t)gr * D + k0 + kk);
      Ht[rr][kk + 0] = hv.x; Ht[rr][kk + 1] = hv.y;
      Ht[rr][kk + 2] = hv.z; Ht[rr][kk + 3] = hv.w;
    }
#pragma unroll
    for (int i = 0; i < 2; ++i) {
      int idx = tid + i * 256;
      if (idx < 320) {
        int c = idx >> 3;
        int kk = (idx & 7) << 2;
        const float4 wv = *reinterpret_cast<const float4*>(W + (size_t)c * D + k0 + kk);
        Wt[c][kk + 0] = wv.x; Wt[c][kk + 1] = wv.y;
        Wt[c][kk + 2] = wv.z; Wt[c][kk + 3] = wv.w;
      }
    }
    __syncthreads();

#pragma unroll
    for (int kk = 0; kk < 32; ++kk) {
      float hv = Ht[r][kk];
#pragma unroll
      for (int ci = 0; ci < 10; ++ci)
        acc[ci] = fmaf(hv, Wt[cg + ci][kk], acc[ci]);
    }
    __syncthreads();
  }

  int gr = row0 + r;
  if (gr < M) {
#pragma unroll
    for (int ci = 0; ci < 10; ++ci)
      out[(size_t)gr * N_CLS + cg + ci] = acc[ci] + bias[cg + ci];
  }
}

// ---------------------------------------------------------------------------
extern "C" void kernel_launch(void* const* d_in, const int* in_sizes, int n_in,
                              void* d_out, int out_size, void* d_ws, size_t ws_size,
                              hipStream_t stream) {
  const float* x   = (const float*)d_in[0];
  const int*   src = (const int*)d_in[1];
  const int*   dst = (const int*)d_in[2];
  const float* W0  = (const float*)d_in[3];
  const float* b0  = (const float*)d_in[4];
  const float* W1  = (const float*)d_in[5];
  const float* b1  = (const float*)d_in[6];
  const float* W2  = (const float*)d_in[7];
  const float* b2  = (const float*)d_in[8];
  float* out = (float*)d_out;

  const int M = in_sizes[0] / D;  // 50000
  const int E = in_sizes[1];      // 600000

  // workspace layout: [t: M*D fp32][hbuf: M*D fp32][counts: M][row_start: M+1][col_idx: E]
  float* t    = (float*)d_ws;
  float* hbuf = t + (size_t)M * D;
  int* counts    = (int*)(hbuf + (size_t)M * D);
  int* row_start = counts + M;
  int* col_idx   = row_start + M + 1;

  const int edgeBlocks = (E + 255) / 256;
  const int gatherBlocks = (M * 64 + 255) / 256;  // 1 wave per node
  const int gemmBlocks = (M + 63) / 64;

  // --- CSR build (int atomics only: 2 x 600k) ---
  hipMemsetAsync(counts, 0, (size_t)M * sizeof(int), stream);
  count_kernel<<<edgeBlocks, 256, 0, stream>>>(dst, counts, E);
  scan_kernel<<<1, 1024, 0, stream>>>(counts, row_start, M, E);
  fill_kernel<<<edgeBlocks, 256, 0, stream>>>(src, dst, counts, col_idx, E);

  // --- Layer 0 ---
  gather_kernel<<<gatherBlocks, 256, 0, stream>>>(x, row_start, col_idx, t, M);
  gemm128_kernel<true><<<gemmBlocks, 256, 0, stream>>>(t, W0, b0, hbuf, M);
  // --- Layer 1 ---
  gather_kernel<<<gatherBlocks, 256, 0, stream>>>(hbuf, row_start, col_idx, t, M);
  gemm128_kernel<true><<<gemmBlocks, 256, 0, stream>>>(t, W1, b1, hbuf, M);
  // --- Layer 2 ---
  gather_kernel<<<gatherBlocks, 256, 0, stream>>>(hbuf, row_start, col_idx, t, M);
  gemm40_kernel<<<gemmBlocks, 256, 0, stream>>>(t, W2, b2, out, M);
}

// Round 3
// 390.973 us; speedup vs baseline: 8.2765x; 1.3574x over previous
//
#include <hip/hip_runtime.h>

#define D 128
#define N_CLS 40

// ---------------------------------------------------------------------------
// CSR build step 1: counts[dst[e]]++
// ---------------------------------------------------------------------------
__global__ __launch_bounds__(256) void count_kernel(
    const int* __restrict__ dst, int* __restrict__ counts, int n_edges) {
  int e = blockIdx.x * 256 + threadIdx.x;
  if (e < n_edges) atomicAdd(&counts[dst[e]], 1);
}

// ---------------------------------------------------------------------------
// 3-phase device-wide exclusive scan over counts[n] (n % 4 == 0).
// Phase A: per-block (1024 elems) partial sums.
// ---------------------------------------------------------------------------
__global__ __launch_bounds__(256) void scan_partA(
    const int* __restrict__ counts, int* __restrict__ partials, int n4) {
  __shared__ int sh[256];
  const int tid = threadIdx.x;
  const int g = blockIdx.x * 256 + tid;
  int s = 0;
  if (g < n4) {
    const int4 c = reinterpret_cast<const int4*>(counts)[g];
    s = c.x + c.y + c.z + c.w;
  }
  sh[tid] = s;
  __syncthreads();
  for (int off = 128; off > 0; off >>= 1) {
    if (tid < off) sh[tid] += sh[tid + off];
    __syncthreads();
  }
  if (tid == 0) partials[blockIdx.x] = sh[0];
}

// Phase B: one wave scans the partials (nP <= 64) -> exclusive, in place.
// Also writes row_start[n] = n_edges.
__global__ __launch_bounds__(64) void scan_partB(
    int* __restrict__ partials, int* __restrict__ row_start, int nP,
    int n, int n_edges) {
  const int lane = threadIdx.x;
  int v = (lane < nP) ? partials[lane] : 0;
  // inclusive wave scan
  int x = v;
  for (int off = 1; off < 64; off <<= 1) {
    int y = __shfl_up(x, off, 64);
    if (lane >= off) x += y;
  }
  if (lane < nP) partials[lane] = x - v;  // exclusive
  if (lane == 0) row_start[n] = n_edges;
}

// Phase C: per-block local exclusive scan + block offset.
// Writes row_start[i] and counts[i] (= cursor for fill_kernel).
__global__ __launch_bounds__(256) void scan_partC(
    int* __restrict__ counts, const int* __restrict__ partials,
    int* __restrict__ row_start, int n4) {
  __shared__ int sh[256];
  const int tid = threadIdx.x;
  const int g = blockIdx.x * 256 + tid;
  int4 c = make_int4(0, 0, 0, 0);
  if (g < n4) c = reinterpret_cast<const int4*>(counts)[g];
  const int s0 = c.x;
  const int s1 = s0 + c.y;
  const int s2 = s1 + c.z;
  const int s3 = s2 + c.w;  // thread total
  sh[tid] = s3;
  __syncthreads();
  // Hillis-Steele inclusive scan over thread totals
  for (int off = 1; off < 256; off <<= 1) {
    int y = (tid >= off) ? sh[tid - off] : 0;
    __syncthreads();
    sh[tid] += y;
    __syncthreads();
  }
  if (g < n4) {
    const int base = partials[blockIdx.x] + sh[tid] - s3;
    const int4 rs = make_int4(base, base + s0, base + s1, base + s2);
    reinterpret_cast<int4*>(row_start)[g] = rs;
    reinterpret_cast<int4*>(counts)[g] = rs;  // cursor
  }
}

// ---------------------------------------------------------------------------
// CSR build step 3: col_idx[cursor[dst[e]]++] = src[e]
// ---------------------------------------------------------------------------
__global__ __launch_bounds__(256) void fill_kernel(
    const int* __restrict__ src, const int* __restrict__ dst,
    int* __restrict__ cursor, int* __restrict__ col_idx, int n_edges) {
  int e = blockIdx.x * 256 + threadIdx.x;
  if (e < n_edges) {
    int p = atomicAdd(&cursor[dst[e]], 1);
    col_idx[p] = src[e];
  }
}

// ---------------------------------------------------------------------------
// Gather-aggregate: out[n] = h[n] + sum_{j in row n} h[col_idx[j]]
// One wave per node; float2 per lane; unroll-4 independent accumulators.
// ---------------------------------------------------------------------------
__global__ __launch_bounds__(256) void gather_kernel(
    const float* __restrict__ h, const int* __restrict__ row_start,
    const int* __restrict__ col_idx, float* __restrict__ out, int n_nodes) {
  int wave = (blockIdx.x * 256 + threadIdx.x) >> 6;
  int lane = threadIdx.x & 63;
  if (wave >= n_nodes) return;
  const float2* hp = reinterpret_cast<const float2*>(h);
  int s = row_start[wave];
  int e = row_start[wave + 1];
  float2 a0 = hp[(size_t)wave * 64 + lane];  // self term
  float2 a1 = make_float2(0.f, 0.f);
  float2 a2 = make_float2(0.f, 0.f);
  float2 a3 = make_float2(0.f, 0.f);
  int j = s;
  for (; j + 3 < e; j += 4) {
    int u0 = col_idx[j + 0];
    int u1 = col_idx[j + 1];
    int u2 = col_idx[j + 2];
    int u3 = col_idx[j + 3];
    float2 v0 = hp[(size_t)u0 * 64 + lane];
    float2 v1 = hp[(size_t)u1 * 64 + lane];
    float2 v2 = hp[(size_t)u2 * 64 + lane];
    float2 v3 = hp[(size_t)u3 * 64 + lane];
    a0.x += v0.x; a0.y += v0.y;
    a1.x += v1.x; a1.y += v1.y;
    a2.x += v2.x; a2.y += v2.y;
    a3.x += v3.x; a3.y += v3.y;
  }
  for (; j < e; ++j) {
    int u = col_idx[j];
    float2 v = hp[(size_t)u * 64 + lane];
    a0.x += v.x; a0.y += v.y;
  }
  a0.x += a1.x + a2.x + a3.x;
  a0.y += a1.y + a2.y + a3.y;
  reinterpret_cast<float2*>(out)[(size_t)wave * 64 + lane] = a0;
}

// ---------------------------------------------------------------------------
// out[M,128] = relu?(HS[M,128] @ W[128,128]^T + b)
// ---------------------------------------------------------------------------
template <bool RELU>
__global__ __launch_bounds__(256) void gemm128_kernel(
    const float* __restrict__ HS, const float* __restrict__ W,
    const float* __restrict__ bias, float* __restrict__ out, int M) {
  __shared__ float Ht[64][33];
  __shared__ float Wt[128][33];
  const int tid = threadIdx.x;
  const int row0 = blockIdx.x * 64;
  const int tr = tid >> 5;
  const int tc = tid & 31;

  float acc[8][4] = {};

  for (int k0 = 0; k0 < D; k0 += 32) {
#pragma unroll
    for (int i = 0; i < 2; ++i) {
      int idx = tid + i * 256;
      int r = idx >> 3;
      int kk = (idx & 7) << 2;
      int gr = row0 + r;
      float4 hv = make_float4(0.f, 0.f, 0.f, 0.f);
      if (gr < M)
        hv = *reinterpret_cast<const float4*>(HS + (size_t)gr * D + k0 + kk);
      Ht[r][kk + 0] = hv.x; Ht[r][kk + 1] = hv.y;
      Ht[r][kk + 2] = hv.z; Ht[r][kk + 3] = hv.w;
    }
#pragma unroll
    for (int i = 0; i < 4; ++i) {
      int idx = tid + i * 256;
      int c = idx >> 3;
      int kk = (idx & 7) << 2;
      const float4 wv = *reinterpret_cast<const float4*>(W + (size_t)c * D + k0 + kk);
      Wt[c][kk + 0] = wv.x; Wt[c][kk + 1] = wv.y;
      Wt[c][kk + 2] = wv.z; Wt[c][kk + 3] = wv.w;
    }
    __syncthreads();

#pragma unroll
    for (int kk = 0; kk < 32; ++kk) {
      float hv[8];
#pragma unroll
      for (int ri = 0; ri < 8; ++ri) hv[ri] = Ht[tr * 8 + ri][kk];
      float wv[4];
#pragma unroll
      for (int ci = 0; ci < 4; ++ci) wv[ci] = Wt[tc + 32 * ci][kk];
#pragma unroll
      for (int ri = 0; ri < 8; ++ri)
#pragma unroll
        for (int ci = 0; ci < 4; ++ci)
          acc[ri][ci] = fmaf(hv[ri], wv[ci], acc[ri][ci]);
    }
    __syncthreads();
  }

#pragma unroll
  for (int ri = 0; ri < 8; ++ri) {
    int gr = row0 + tr * 8 + ri;
    if (gr >= M) continue;
#pragma unroll
    for (int ci = 0; ci < 4; ++ci) {
      int c = tc + 32 * ci;
      float v = acc[ri][ci] + bias[c];
      if (RELU) v = fmaxf(v, 0.f);
      out[(size_t)gr * D + c] = v;
    }
  }
}

// ---------------------------------------------------------------------------
// out[M,40] = HS[M,128] @ W[40,128]^T + b
// ---------------------------------------------------------------------------
__global__ __launch_bounds__(256) void gemm40_kernel(
    const float* __restrict__ HS, const float* __restrict__ W,
    const float* __restrict__ bias, float* __restrict__ out, int M) {
  __shared__ float Ht[64][33];
  __shared__ float Wt[40][33];
  const int tid = threadIdx.x;
  const int row0 = blockIdx.x * 64;
  const int r = tid >> 2;
  const int cg = (tid & 3) * 10;

  float acc[10] = {};

  for (int k0 = 0; k0 < D; k0 += 32) {
#pragma unroll
    for (int i = 0; i < 2; ++i) {
      int idx = tid + i * 256;
      int rr = idx >> 3;
      int kk = (idx & 7) << 2;
      int gr = row0 + rr;
      float4 hv = make_float4(0.f, 0.f, 0.f, 0.f);
      if (gr < M)
        hv = *reinterpret_cast<const float4*>(HS + (size_t)gr * D + k0 + kk);
      Ht[rr][kk + 0] = hv.x; Ht[rr][kk + 1] = hv.y;
      Ht[rr][kk + 2] = hv.z; Ht[rr][kk + 3] = hv.w;
    }
#pragma unroll
    for (int i = 0; i < 2; ++i) {
      int idx = tid + i * 256;
      if (idx < 320) {
        int c = idx >> 3;
        int kk = (idx & 7) << 2;
        const float4 wv = *reinterpret_cast<const float4*>(W + (size_t)c * D + k0 + kk);
        Wt[c][kk + 0] = wv.x; Wt[c][kk + 1] = wv.y;
        Wt[c][kk + 2] = wv.z; Wt[c][kk + 3] = wv.w;
      }
    }
    __syncthreads();

#pragma unroll
    for (int kk = 0; kk < 32; ++kk) {
      float hv = Ht[r][kk];
#pragma unroll
      for (int ci = 0; ci < 10; ++ci)
        acc[ci] = fmaf(hv, Wt[cg + ci][kk], acc[ci]);
    }
    __syncthreads();
  }

  int gr = row0 + r;
  if (gr < M) {
#pragma unroll
    for (int ci = 0; ci < 10; ++ci)
      out[(size_t)gr * N_CLS + cg + ci] = acc[ci] + bias[cg + ci];
  }
}

// ---------------------------------------------------------------------------
extern "C" void kernel_launch(void* const* d_in, const int* in_sizes, int n_in,
                              void* d_out, int out_size, void* d_ws, size_t ws_size,
                              hipStream_t stream) {
  const float* x   = (const float*)d_in[0];
  const int*   src = (const int*)d_in[1];
  const int*   dst = (const int*)d_in[2];
  const float* W0  = (const float*)d_in[3];
  const float* b0  = (const float*)d_in[4];
  const float* W1  = (const float*)d_in[5];
  const float* b1  = (const float*)d_in[6];
  const float* W2  = (const float*)d_in[7];
  const float* b2  = (const float*)d_in[8];
  float* out = (float*)d_out;

  const int M = in_sizes[0] / D;  // 50000 (divisible by 4)
  const int E = in_sizes[1];      // 600000

  // ws layout: [t: M*D][hbuf: M*D][counts: M][row_start: M+1 (+pad3)][col_idx: E][partials: 64]
  float* t    = (float*)d_ws;
  float* hbuf = t + (size_t)M * D;
  int* counts    = (int*)(hbuf + (size_t)M * D);
  int* row_start = counts + M;
  int* col_idx   = row_start + M + 4;  // keep int4 alignment
  int* partials  = col_idx + E;

  const int n4 = M / 4;                       // 12500 int4 slots
  const int scanBlocks = (n4 + 255) / 256;    // 49
  const int edgeBlocks = (E + 255) / 256;
  const int gatherBlocks = (M * 64 + 255) / 256;
  const int gemmBlocks = (M + 63) / 64;

  // --- CSR build ---
  hipMemsetAsync(counts, 0, (size_t)M * sizeof(int), stream);
  count_kernel<<<edgeBlocks, 256, 0, stream>>>(dst, counts, E);
  scan_partA<<<scanBlocks, 256, 0, stream>>>(counts, partials, n4);
  scan_partB<<<1, 64, 0, stream>>>(partials, row_start, scanBlocks, M, E);
  scan_partC<<<scanBlocks, 256, 0, stream>>>(counts, partials, row_start, n4);
  fill_kernel<<<edgeBlocks, 256, 0, stream>>>(src, dst, counts, col_idx, E);

  // --- Layer 0 ---
  gather_kernel<<<gatherBlocks, 256, 0, stream>>>(x, row_start, col_idx, t, M);
  gemm128_kernel<true><<<gemmBlocks, 256, 0, stream>>>(t, W0, b0, hbuf, M);
  // --- Layer 1 ---
  gather_kernel<<<gatherBlocks, 256, 0, stream>>>(hbuf, row_start, col_idx, t, M);
  gemm128_kernel<true><<<gemmBlocks, 256, 0, stream>>>(t, W1, b1, hbuf, M);
  // --- Layer 2 ---
  gather_kernel<<<gatherBlocks, 256, 0, stream>>>(hbuf, row_start, col_idx, t, M);
  gemm40_kernel<<<gemmBlocks, 256, 0, stream>>>(t, W2, b2, out, M);
}

// Round 4
// 309.857 us; speedup vs baseline: 10.4432x; 1.2618x over previous
//
#include <hip/hip_runtime.h>

#define D 128
#define N_CLS 40

// ---------------------------------------------------------------------------
// bf16 helpers (RNE)
// ---------------------------------------------------------------------------
__device__ __forceinline__ unsigned f2bf(float f) {
  unsigned u = __builtin_bit_cast(unsigned, f);
  u += 0x7fffu + ((u >> 16) & 1u);
  return u >> 16;
}
__device__ __forceinline__ float bf_lo(unsigned u) {
  return __builtin_bit_cast(float, u << 16);
}
__device__ __forceinline__ float bf_hi(unsigned u) {
  return __builtin_bit_cast(float, u & 0xffff0000u);
}

// ---------------------------------------------------------------------------
// CSR build step 1: counts[dst[e]]++
// ---------------------------------------------------------------------------
__global__ __launch_bounds__(256) void count_kernel(
    const int* __restrict__ dst, int* __restrict__ counts, int n_edges) {
  int e = blockIdx.x * 256 + threadIdx.x;
  if (e < n_edges) atomicAdd(&counts[dst[e]], 1);
}

// 3-phase device-wide exclusive scan over counts[n] (n % 4 == 0).
__global__ __launch_bounds__(256) void scan_partA(
    const int* __restrict__ counts, int* __restrict__ partials, int n4) {
  __shared__ int sh[256];
  const int tid = threadIdx.x;
  const int g = blockIdx.x * 256 + tid;
  int s = 0;
  if (g < n4) {
    const int4 c = reinterpret_cast<const int4*>(counts)[g];
    s = c.x + c.y + c.z + c.w;
  }
  sh[tid] = s;
  __syncthreads();
  for (int off = 128; off > 0; off >>= 1) {
    if (tid < off) sh[tid] += sh[tid + off];
    __syncthreads();
  }
  if (tid == 0) partials[blockIdx.x] = sh[0];
}

__global__ __launch_bounds__(64) void scan_partB(
    int* __restrict__ partials, int* __restrict__ row_start, int nP,
    int n, int n_edges) {
  const int lane = threadIdx.x;
  int v = (lane < nP) ? partials[lane] : 0;
  int x = v;
  for (int off = 1; off < 64; off <<= 1) {
    int y = __shfl_up(x, off, 64);
    if (lane >= off) x += y;
  }
  if (lane < nP) partials[lane] = x - v;
  if (lane == 0) row_start[n] = n_edges;
}

__global__ __launch_bounds__(256) void scan_partC(
    int* __restrict__ counts, const int* __restrict__ partials,
    int* __restrict__ row_start, int n4) {
  __shared__ int sh[256];
  const int tid = threadIdx.x;
  const int g = blockIdx.x * 256 + tid;
  int4 c = make_int4(0, 0, 0, 0);
  if (g < n4) c = reinterpret_cast<const int4*>(counts)[g];
  const int s0 = c.x;
  const int s1 = s0 + c.y;
  const int s2 = s1 + c.z;
  const int s3 = s2 + c.w;
  sh[tid] = s3;
  __syncthreads();
  for (int off = 1; off < 256; off <<= 1) {
    int y = (tid >= off) ? sh[tid - off] : 0;
    __syncthreads();
    sh[tid] += y;
    __syncthreads();
  }
  if (g < n4) {
    const int base = partials[blockIdx.x] + sh[tid] - s3;
    const int4 rs = make_int4(base, base + s0, base + s1, base + s2);
    reinterpret_cast<int4*>(row_start)[g] = rs;
    reinterpret_cast<int4*>(counts)[g] = rs;
  }
}

__global__ __launch_bounds__(256) void fill_kernel(
    const int* __restrict__ src, const int* __restrict__ dst,
    int* __restrict__ cursor, int* __restrict__ col_idx, int n_edges) {
  int e = blockIdx.x * 256 + threadIdx.x;
  if (e < n_edges) {
    int p = atomicAdd(&cursor[dst[e]], 1);
    col_idx[p] = src[e];
  }
}

// ---------------------------------------------------------------------------
// Converters
// ---------------------------------------------------------------------------
__global__ __launch_bounds__(256) void convert_x_kernel(
    const float4* __restrict__ in, uint2* __restrict__ out, int n4) {
  int i = blockIdx.x * 256 + threadIdx.x;
  if (i < n4) {
    float4 v = in[i];
    out[i] = make_uint2(f2bf(v.x) | (f2bf(v.y) << 16),
                        f2bf(v.z) | (f2bf(v.w) << 16));
  }
}

// W0 (128x128), W1 (128x128), W2 padded to 48x128 (rows 40..47 = 0)
__global__ __launch_bounds__(256) void convert_w_kernel(
    const float* __restrict__ W0, const float* __restrict__ W1,
    const float* __restrict__ W2, unsigned short* __restrict__ W0b,
    unsigned short* __restrict__ W1b, unsigned short* __restrict__ W2b) {
  int idx = blockIdx.x * 256 + threadIdx.x;
  const int n0 = 128 * 128, n1 = 128 * 128, n2 = 48 * 128;
  if (idx < n0) {
    W0b[idx] = (unsigned short)f2bf(W0[idx]);
  } else if (idx < n0 + n1) {
    int i = idx - n0;
    W1b[i] = (unsigned short)f2bf(W1[i]);
  } else if (idx < n0 + n1 + n2) {
    int i = idx - n0 - n1;
    int r = i >> 7;
    W2b[i] = (r < N_CLS) ? (unsigned short)f2bf(W2[i]) : (unsigned short)0;
  }
}

// ---------------------------------------------------------------------------
// Gather-aggregate in bf16: out[n] = h[n] + sum_{j in row n} h[col_idx[j]]
// One wave per node; 1 dword (2 bf16) per lane; fp32 accumulation.
// ---------------------------------------------------------------------------
__global__ __launch_bounds__(256) void gather_bf16(
    const unsigned* __restrict__ h, const int* __restrict__ row_start,
    const int* __restrict__ col_idx, unsigned* __restrict__ out, int n_nodes) {
  int wave = (blockIdx.x * 256 + threadIdx.x) >> 6;
  int lane = threadIdx.x & 63;
  if (wave >= n_nodes) return;
  int s = row_start[wave];
  int e = row_start[wave + 1];
  unsigned su = h[(size_t)wave * 64 + lane];  // self term
  float a0x = bf_lo(su), a0y = bf_hi(su);
  float a1x = 0.f, a1y = 0.f, a2x = 0.f, a2y = 0.f, a3x = 0.f, a3y = 0.f;
  int j = s;
  for (; j + 3 < e; j += 4) {
    int u0 = col_idx[j + 0];
    int u1 = col_idx[j + 1];
    int u2 = col_idx[j + 2];
    int u3 = col_idx[j + 3];
    unsigned v0 = h[(size_t)u0 * 64 + lane];
    unsigned v1 = h[(size_t)u1 * 64 + lane];
    unsigned v2 = h[(size_t)u2 * 64 + lane];
    unsigned v3 = h[(size_t)u3 * 64 + lane];
    a0x += bf_lo(v0); a0y += bf_hi(v0);
    a1x += bf_lo(v1); a1y += bf_hi(v1);
    a2x += bf_lo(v2); a2y += bf_hi(v2);
    a3x += bf_lo(v3); a3y += bf_hi(v3);
  }
  for (; j < e; ++j) {
    unsigned v = h[(size_t)col_idx[j] * 64 + lane];
    a0x += bf_lo(v); a0y += bf_hi(v);
  }
  a0x += a1x + a2x + a3x;
  a0y += a1y + a2y + a3y;
  out[(size_t)wave * 64 + lane] = f2bf(a0x) | (f2bf(a0y) << 16);
}

// ---------------------------------------------------------------------------
// MFMA GEMM: out[M, ncols] = act(A[M,128] @ B[NT*16,128]^T + bias)
// A, B bf16 row-major (K=128 contiguous). Block = 256 thr = 4 waves, 64 rows.
// Wave w: rows blk*64 + w*16 .. +15, all NT n-tiles, K swept in 4 steps of 32.
// A-frag & B-frag: lane holds row (lane&15), k = (lane>>4)*8 + j  (16B loads).
// C/D: col = lane&15, row = (lane>>4)*4 + reg.
// ---------------------------------------------------------------------------
typedef __attribute__((ext_vector_type(8))) short bf16x8;
typedef __attribute__((ext_vector_type(4))) float f32x4;

template <int NT, bool RELU, bool OUTBF16>
__global__ __launch_bounds__(256) void gemm_mfma(
    const unsigned short* __restrict__ A, const unsigned short* __restrict__ B,
    const float* __restrict__ bias, void* __restrict__ out, int M, int ncols) {
  const int tid = threadIdx.x;
  const int wv = tid >> 6;
  const int lane = tid & 63;
  const int m_base = blockIdx.x * 64 + wv * 16;
  const int r16 = lane & 15;
  const int quad = lane >> 4;

  // A fragments for all 4 k-steps (rows may run past M; reads stay inside ws)
  const short* Ap = (const short*)A + (size_t)(m_base + r16) * D + quad * 8;
  bf16x8 af[4];
#pragma unroll
  for (int ks = 0; ks < 4; ++ks)
    af[ks] = *reinterpret_cast<const bf16x8*>(Ap + ks * 32);

  f32x4 acc[NT];
#pragma unroll
  for (int nt = 0; nt < NT; ++nt) {
    acc[nt] = (f32x4){0.f, 0.f, 0.f, 0.f};
    const short* Bp = (const short*)B + (size_t)(nt * 16 + r16) * D + quad * 8;
#pragma unroll
    for (int ks = 0; ks < 4; ++ks) {
      bf16x8 bf = *reinterpret_cast<const bf16x8*>(Bp + ks * 32);
      acc[nt] = __builtin_amdgcn_mfma_f32_16x16x32_bf16(af[ks], bf, acc[nt], 0, 0, 0);
    }
  }

  const int orow = m_base + quad * 4;
#pragma unroll
  for (int nt = 0; nt < NT; ++nt) {
    int col = nt * 16 + r16;
#pragma unroll
    for (int r = 0; r < 4; ++r) {
      int grow = orow + r;
      if (grow < M && col < ncols) {
        float v = acc[nt][r] + bias[col];
        if (RELU) v = fmaxf(v, 0.f);
        if (OUTBF16)
          ((unsigned short*)out)[(size_t)grow * D + col] = (unsigned short)f2bf(v);
        else
          ((float*)out)[(size_t)grow * ncols + col] = v;
      }
    }
  }
}

// ---------------------------------------------------------------------------
extern "C" void kernel_launch(void* const* d_in, const int* in_sizes, int n_in,
                              void* d_out, int out_size, void* d_ws, size_t ws_size,
                              hipStream_t stream) {
  const float* x   = (const float*)d_in[0];
  const int*   src = (const int*)d_in[1];
  const int*   dst = (const int*)d_in[2];
  const float* W0  = (const float*)d_in[3];
  const float* b0  = (const float*)d_in[4];
  const float* W1  = (const float*)d_in[5];
  const float* b1  = (const float*)d_in[6];
  const float* W2  = (const float*)d_in[7];
  const float* b2  = (const float*)d_in[8];
  float* out = (float*)d_out;

  const int M = in_sizes[0] / D;  // 50000
  const int E = in_sizes[1];      // 600000

  // ws layout (16B-aligned chunks):
  // [t bf16 M*128][hb bf16 M*128][xb bf16 M*128][W0b 128x128][W1b 128x128]
  // [W2b 48x128][counts M][row_start M+4][col_idx E][partials 64]
  char* p = (char*)d_ws;
  unsigned* t  = (unsigned*)p;  p += (size_t)M * D * 2;
  unsigned* hb = (unsigned*)p;  p += (size_t)M * D * 2;
  unsigned* xb = (unsigned*)p;  p += (size_t)M * D * 2;
  unsigned short* W0b = (unsigned short*)p;  p += 128 * 128 * 2;
  unsigned short* W1b = (unsigned short*)p;  p += 128 * 128 * 2;
  unsigned short* W2b = (unsigned short*)p;  p += 48 * 128 * 2;
  int* counts    = (int*)p;  p += (size_t)M * 4;
  int* row_start = (int*)p;  p += (size_t)(M + 4) * 4;
  int* col_idx   = (int*)p;  p += (size_t)E * 4;
  int* partials  = (int*)p;

  const int n4 = M / 4;
  const int scanBlocks = (n4 + 255) / 256;
  const int edgeBlocks = (E + 255) / 256;
  const int gatherBlocks = (M * 64 + 255) / 256;
  const int gemmBlocks = (M + 63) / 64;
  const int convXBlocks = ((M * D / 4) + 255) / 256;
  const int convWBlocks = (128 * 128 * 2 + 48 * 128 + 255) / 256;

  // --- CSR build ---
  hipMemsetAsync(counts, 0, (size_t)M * sizeof(int), stream);
  count_kernel<<<edgeBlocks, 256, 0, stream>>>(dst, counts, E);
  scan_partA<<<scanBlocks, 256, 0, stream>>>(counts, partials, n4);
  scan_partB<<<1, 64, 0, stream>>>(partials, row_start, scanBlocks, M, E);
  scan_partC<<<scanBlocks, 256, 0, stream>>>(counts, partials, row_start, n4);
  fill_kernel<<<edgeBlocks, 256, 0, stream>>>(src, dst, counts, col_idx, E);

  // --- Converters ---
  convert_x_kernel<<<convXBlocks, 256, 0, stream>>>(
      (const float4*)x, (uint2*)xb, M * D / 4);
  convert_w_kernel<<<convWBlocks, 256, 0, stream>>>(W0, W1, W2, W0b, W1b, W2b);

  // --- Layer 0 ---
  gather_bf16<<<gatherBlocks, 256, 0, stream>>>(xb, row_start, col_idx, t, M);
  gemm_mfma<8, true, true><<<gemmBlocks, 256, 0, stream>>>(
      (const unsigned short*)t, W0b, b0, hb, M, D);
  // --- Layer 1 ---
  gather_bf16<<<gatherBlocks, 256, 0, stream>>>(hb, row_start, col_idx, t, M);
  gemm_mfma<8, true, true><<<gemmBlocks, 256, 0, stream>>>(
      (const unsigned short*)t, W1b, b1, hb, M, D);
  // --- Layer 2 (fp32 out, no relu) ---
  gather_bf16<<<gatherBlocks, 256, 0, stream>>>(hb, row_start, col_idx, t, M);
  gemm_mfma<3, false, false><<<gemmBlocks, 256, 0, stream>>>(
      (const unsigned short*)t, W2b, b2, out, M, N_CLS);
}